// Round 1
// baseline (906.500 us; speedup 1.0000x reference)
//
#include <hip/hip_runtime.h>
#include <hip/hip_bf16.h>

#define KS 5
#define K3 125

// ---------------------------------------------------------------------------
// Spline basis: per edge, degree-1 open B-spline over 3D pseudo coords.
// basis[e*8+s], widx[e*8+s]
// ---------------------------------------------------------------------------
__global__ void basis_kernel(const float* __restrict__ pseudo,
                             float* __restrict__ basis, int* __restrict__ widx,
                             int E) {
    int e = blockIdx.x * blockDim.x + threadIdx.x;
    if (e >= E) return;
    float fr[3];
    int bot[3];
#pragma unroll
    for (int d = 0; d < 3; ++d) {
        float v = pseudo[e * 3 + d] * (float)(KS - 1);
        float fl = fminf(floorf(v), (float)(KS - 2));
        fr[d] = v - fl;
        bot[d] = (int)fl;
    }
    const int strides[3] = {1, KS, KS * KS};
#pragma unroll
    for (int s = 0; s < 8; ++s) {
        float b = 1.f;
        int w = 0;
#pragma unroll
        for (int d = 0; d < 3; ++d) {
            int bit = (s >> d) & 1;
            b *= bit ? fr[d] : (1.f - fr[d]);
            w += (bot[d] + bit) * strides[d];
        }
        basis[e * 8 + s] = b;
        widx[e * 8 + s] = w;
    }
}

__global__ void deg_kernel(const int* __restrict__ dst, float* __restrict__ deg, int E) {
    int e = blockIdx.x * blockDim.x + threadIdx.x;
    if (e >= E) return;
    atomicAdd(&deg[dst[e]], 1.0f);
}

// ---------------------------------------------------------------------------
// Edge-centric spline conv scatter: one (sub-)wave of OUT_C lanes per edge.
// out[dst, o] += sum_s basis_s * sum_i x[src, i] * W[k_s, i, o]
// ---------------------------------------------------------------------------
template <int IN_C, int OUT_C>
__global__ __launch_bounds__(256) void conv_edges(
    const float* __restrict__ x, const int* __restrict__ src,
    const int* __restrict__ dst, const float* __restrict__ basis,
    const int* __restrict__ widx, const float* __restrict__ W,
    float* __restrict__ out, int E) {
    const int lane = threadIdx.x & 63;
    const int wid = threadIdx.x >> 6;
    constexpr int EPW = 64 / OUT_C;  // edges per wave (1 or 2)
    const int sub = (EPW == 2) ? (lane >> 5) : 0;
    const int o = lane & (OUT_C - 1);
    long e = (long)(blockIdx.x * (blockDim.x >> 6) + wid) * EPW + sub;
    if (e >= E) return;
    const int s_ = src[e];
    const int d_ = dst[e];
    float xv = (o < IN_C) ? x[s_ * IN_C + o] : 0.f;  // this lane's share of x row
    float acc = 0.f;
#pragma unroll
    for (int s = 0; s < 8; ++s) {
        const float b = basis[e * 8 + s];
        const int k = widx[e * 8 + s];
        const float* Wk = W + (long)k * IN_C * OUT_C;
#pragma unroll 4
        for (int i = 0; i < IN_C; ++i) {
            float xi = __shfl(xv, i, OUT_C);
            acc = fmaf(b * xi, Wk[i * OUT_C + o], acc);
        }
    }
    atomicAdd(&out[(long)d_ * OUT_C + o], acc);
}

// ---------------------------------------------------------------------------
// Finalize: out = scatter/max(deg,1) + x@R + B, then ELU.  In-place on out.
// ---------------------------------------------------------------------------
template <int IN_C, int OUT_C>
__global__ __launch_bounds__(256) void finalize_k(
    const float* __restrict__ xin, const float* __restrict__ R,
    const float* __restrict__ B, const float* __restrict__ deg,
    float* __restrict__ out, int n) {
    const int lane = threadIdx.x & 63;
    const int wid = threadIdx.x >> 6;
    constexpr int EPW = 64 / OUT_C;
    const int sub = (EPW == 2) ? (lane >> 5) : 0;
    const int o = lane & (OUT_C - 1);
    int j = (blockIdx.x * (blockDim.x >> 6) + wid) * EPW + sub;
    if (j >= n) return;
    float xv = (o < IN_C) ? xin[j * IN_C + o] : 0.f;
    float acc = B[o];
#pragma unroll 4
    for (int i = 0; i < IN_C; ++i) {
        float xi = __shfl(xv, i, OUT_C);
        acc = fmaf(xi, R[i * OUT_C + o], acc);
    }
    float d = fmaxf(deg[j], 1.f);
    float v = out[j * OUT_C + o] / d + acc;
    out[j * OUT_C + o] = (v > 0.f) ? v : expm1f(v);
}

// ---------------------------------------------------------------------------
// Segment max pooling via monotone uint atomicMax.
// enc(f): order-preserving float->uint. Init 0 is below all finite encodings;
// every cluster has exactly n/m members so every slot gets written.
// ---------------------------------------------------------------------------
__global__ void pool_scatter(const float* __restrict__ h, const int* __restrict__ cluster,
                             unsigned* __restrict__ pool, int n, int logC) {
    int idx = blockIdx.x * blockDim.x + threadIdx.x;
    if (idx >= (n << logC)) return;
    int j = idx >> logC;
    int c = idx & ((1 << logC) - 1);
    float f = h[idx];
    int b = __float_as_int(f);
    unsigned enc = (b >= 0) ? ((unsigned)b | 0x80000000u) : ~((unsigned)b);
    atomicMax(&pool[(cluster[j] << logC) + c], enc);
}

__global__ void pool_decode(const unsigned* __restrict__ pool, float* __restrict__ out, int total) {
    int idx = blockIdx.x * blockDim.x + threadIdx.x;
    if (idx >= total) return;
    unsigned u = pool[idx];
    int b = (u & 0x80000000u) ? (int)(u & 0x7FFFFFFFu) : (int)(~u);
    out[idx] = __int_as_float(b);
}

// ---------------------------------------------------------------------------
// Head: mean over 64 nodes -> fc1 (64x64) -> fc2 (64x10) -> log_softmax.
// Single block of 64 threads.
// ---------------------------------------------------------------------------
__global__ void head_kernel(const float* __restrict__ h, const float* __restrict__ fc1w,
                            const float* __restrict__ fc1b, const float* __restrict__ fc2w,
                            const float* __restrict__ fc2b, float* __restrict__ out) {
    __shared__ float m[64], t[64], u[10];
    int lane = threadIdx.x;
    float s = 0.f;
    for (int j = 0; j < 64; ++j) s += h[j * 64 + lane];
    m[lane] = s * (1.f / 64.f);
    __syncthreads();
    float a = fc1b[lane];
    for (int i = 0; i < 64; ++i) a = fmaf(m[i], fc1w[i * 64 + lane], a);
    t[lane] = a;
    __syncthreads();
    if (lane < 10) {
        float b = fc2b[lane];
        for (int i = 0; i < 64; ++i) b = fmaf(t[i], fc2w[i * 10 + lane], b);
        u[lane] = b;
    }
    __syncthreads();
    if (lane < 10) {
        float mx = u[0];
        for (int i = 1; i < 10; ++i) mx = fmaxf(mx, u[i]);
        float se = 0.f;
        for (int i = 0; i < 10; ++i) se += expf(u[i] - mx);
        out[lane] = u[lane] - mx - logf(se);
    }
}

// ---------------------------------------------------------------------------
// Launcher
// ---------------------------------------------------------------------------
extern "C" void kernel_launch(void* const* d_in, const int* in_sizes, int n_in,
                              void* d_out, int out_size, void* d_ws, size_t ws_size,
                              hipStream_t stream) {
    // ---- inputs (setup_inputs dict order) ----
    const float* x = (const float*)d_in[0];
    const int* src[4] = {(const int*)d_in[1], (const int*)d_in[5], (const int*)d_in[9], (const int*)d_in[13]};
    const int* dst[4] = {(const int*)d_in[2], (const int*)d_in[6], (const int*)d_in[10], (const int*)d_in[14]};
    const float* pseudo[4] = {(const float*)d_in[3], (const float*)d_in[7], (const float*)d_in[11], (const float*)d_in[15]};
    const int* cluster[4] = {(const int*)d_in[4], (const int*)d_in[8], (const int*)d_in[12], (const int*)d_in[16]};
    const float* Wp[8], *Rp[8], *Bp[8];
    for (int l = 0; l < 8; ++l) {
        Wp[l] = (const float*)d_in[17 + 3 * l];
        Rp[l] = (const float*)d_in[18 + 3 * l];
        Bp[l] = (const float*)d_in[19 + 3 * l];
    }
    const float* fc1w = (const float*)d_in[41];
    const float* fc1b = (const float*)d_in[42];
    const float* fc2w = (const float*)d_in[43];
    const float* fc2b = (const float*)d_in[44];
    float* outp = (float*)d_out;

    const int NS[5] = {16384, 4096, 1024, 256, 64};
    const int ES[4] = {16384 * 8, 4096 * 8, 1024 * 8, 256 * 8};

    // ---- workspace layout ----
    char* w = (char*)d_ws;
    float* basis = (float*)w;      w += (size_t)ES[0] * 8 * 4;     // 4 MB
    int* widx = (int*)w;           w += (size_t)ES[0] * 8 * 4;     // 4 MB
    float* deg = (float*)w;        w += (size_t)NS[0] * 4;         // 64 KB
    float* bufA = (float*)w;       w += (size_t)NS[0] * 64 * 4;    // 4 MB
    float* bufB = (float*)w;       w += (size_t)NS[0] * 64 * 4;    // 4 MB
    unsigned* pool = (unsigned*)w; w += (size_t)NS[1] * 64 * 4;    // 1 MB

    const int TB = 256;
    auto cdiv = [](int a, int b) { return (a + b - 1) / b; };

    // ============================ Level 0 (n=16384, C 1->32->32) ============
    {
        int E = ES[0], n = NS[0];
        basis_kernel<<<cdiv(E, TB), TB, 0, stream>>>(pseudo[0], basis, widx, E);
        hipMemsetAsync(deg, 0, n * 4, stream);
        deg_kernel<<<cdiv(E, TB), TB, 0, stream>>>(dst[0], deg, E);

        // conv1: 1 -> 32  (x -> bufA)
        hipMemsetAsync(bufA, 0, (size_t)n * 32 * 4, stream);
        conv_edges<1, 32><<<cdiv(E, 8), TB, 0, stream>>>(x, src[0], dst[0], basis, widx, Wp[0], bufA, E);
        finalize_k<1, 32><<<cdiv(n, 8), TB, 0, stream>>>(x, Rp[0], Bp[0], deg, bufA, n);

        // conv12: 32 -> 32 (bufA -> bufB)
        hipMemsetAsync(bufB, 0, (size_t)n * 32 * 4, stream);
        conv_edges<32, 32><<<cdiv(E, 8), TB, 0, stream>>>(bufA, src[0], dst[0], basis, widx, Wp[1], bufB, E);
        finalize_k<32, 32><<<cdiv(n, 8), TB, 0, stream>>>(bufA, Rp[1], Bp[1], deg, bufB, n);

        // pool -> bufA (4096 x 32)
        hipMemsetAsync(pool, 0, (size_t)NS[1] * 32 * 4, stream);
        pool_scatter<<<cdiv(n * 32, TB), TB, 0, stream>>>(bufB, cluster[0], pool, n, 5);
        pool_decode<<<cdiv(NS[1] * 32, TB), TB, 0, stream>>>(pool, bufA, NS[1] * 32);
    }
    // ============================ Level 1 (n=4096, C 32->64->64) ============
    {
        int E = ES[1], n = NS[1];
        basis_kernel<<<cdiv(E, TB), TB, 0, stream>>>(pseudo[1], basis, widx, E);
        hipMemsetAsync(deg, 0, n * 4, stream);
        deg_kernel<<<cdiv(E, TB), TB, 0, stream>>>(dst[1], deg, E);

        hipMemsetAsync(bufB, 0, (size_t)n * 64 * 4, stream);
        conv_edges<32, 64><<<cdiv(E, 4), TB, 0, stream>>>(bufA, src[1], dst[1], basis, widx, Wp[2], bufB, E);
        finalize_k<32, 64><<<cdiv(n, 4), TB, 0, stream>>>(bufA, Rp[2], Bp[2], deg, bufB, n);

        hipMemsetAsync(bufA, 0, (size_t)n * 64 * 4, stream);
        conv_edges<64, 64><<<cdiv(E, 4), TB, 0, stream>>>(bufB, src[1], dst[1], basis, widx, Wp[3], bufA, E);
        finalize_k<64, 64><<<cdiv(n, 4), TB, 0, stream>>>(bufB, Rp[3], Bp[3], deg, bufA, n);

        hipMemsetAsync(pool, 0, (size_t)NS[2] * 64 * 4, stream);
        pool_scatter<<<cdiv(n * 64, TB), TB, 0, stream>>>(bufA, cluster[1], pool, n, 6);
        pool_decode<<<cdiv(NS[2] * 64, TB), TB, 0, stream>>>(pool, bufB, NS[2] * 64);
    }
    // ============================ Level 2 (n=1024, C 64->64->64) ============
    {
        int E = ES[2], n = NS[2];
        basis_kernel<<<cdiv(E, TB), TB, 0, stream>>>(pseudo[2], basis, widx, E);
        hipMemsetAsync(deg, 0, n * 4, stream);
        deg_kernel<<<cdiv(E, TB), TB, 0, stream>>>(dst[2], deg, E);

        hipMemsetAsync(bufA, 0, (size_t)n * 64 * 4, stream);
        conv_edges<64, 64><<<cdiv(E, 4), TB, 0, stream>>>(bufB, src[2], dst[2], basis, widx, Wp[4], bufA, E);
        finalize_k<64, 64><<<cdiv(n, 4), TB, 0, stream>>>(bufB, Rp[4], Bp[4], deg, bufA, n);

        hipMemsetAsync(bufB, 0, (size_t)n * 64 * 4, stream);
        conv_edges<64, 64><<<cdiv(E, 4), TB, 0, stream>>>(bufA, src[2], dst[2], basis, widx, Wp[5], bufB, E);
        finalize_k<64, 64><<<cdiv(n, 4), TB, 0, stream>>>(bufA, Rp[5], Bp[5], deg, bufB, n);

        hipMemsetAsync(pool, 0, (size_t)NS[3] * 64 * 4, stream);
        pool_scatter<<<cdiv(n * 64, TB), TB, 0, stream>>>(bufB, cluster[2], pool, n, 6);
        pool_decode<<<cdiv(NS[3] * 64, TB), TB, 0, stream>>>(pool, bufA, NS[3] * 64);
    }
    // ============================ Level 3 (n=256, C 64->64->64) =============
    {
        int E = ES[3], n = NS[3];
        basis_kernel<<<cdiv(E, TB), TB, 0, stream>>>(pseudo[3], basis, widx, E);
        hipMemsetAsync(deg, 0, n * 4, stream);
        deg_kernel<<<cdiv(E, TB), TB, 0, stream>>>(dst[3], deg, E);

        hipMemsetAsync(bufB, 0, (size_t)n * 64 * 4, stream);
        conv_edges<64, 64><<<cdiv(E, 4), TB, 0, stream>>>(bufA, src[3], dst[3], basis, widx, Wp[6], bufB, E);
        finalize_k<64, 64><<<cdiv(n, 4), TB, 0, stream>>>(bufA, Rp[6], Bp[6], deg, bufB, n);

        hipMemsetAsync(bufA, 0, (size_t)n * 64 * 4, stream);
        conv_edges<64, 64><<<cdiv(E, 4), TB, 0, stream>>>(bufB, src[3], dst[3], basis, widx, Wp[7], bufA, E);
        finalize_k<64, 64><<<cdiv(n, 4), TB, 0, stream>>>(bufB, Rp[7], Bp[7], deg, bufA, n);

        hipMemsetAsync(pool, 0, (size_t)NS[4] * 64 * 4, stream);
        pool_scatter<<<cdiv(n * 64, TB), TB, 0, stream>>>(bufA, cluster[3], pool, n, 6);
        pool_decode<<<cdiv(NS[4] * 64, TB), TB, 0, stream>>>(pool, bufB, NS[4] * 64);
    }
    // ============================ Head ======================================
    head_kernel<<<1, 64, 0, stream>>>(bufB, fc1w, fc1b, fc2w, fc2b, outp);
}